// Round 11
// baseline (779.841 us; speedup 1.0000x reference)
//
#include <hip/hip_runtime.h>
#include <math.h>

#define NN 1024
#define LOG2E 1.4426950408889634f

template <int CTRL>
__device__ __forceinline__ float dpp_mov(float x) {
    int xi = __builtin_bit_cast(int, x);
    int r = __builtin_amdgcn_update_dpp(0, xi, CTRL, 0xF, 0xF, true);
    return __builtin_bit_cast(float, r);
}
__device__ __forceinline__ float dpp_rowsum16(float t) {
    t += dpp_mov<0x111>(t);
    t += dpp_mov<0x112>(t);
    t += dpp_mov<0x114>(t);
    t += dpp_mov<0x118>(t);
    return t;
}
__device__ __forceinline__ float quad_sum4(float t) {
    t += dpp_mov<0xB1>(t);   // quad_perm [1,0,3,2]
    t += dpp_mov<0x4E>(t);   // quad_perm [2,3,0,1]
    return t;
}

// --- one 32(i) x 16(j) adjacency tile per task ----------------------------
// (emb_i.emb_j != 0) <=> (ne_i.ne_j != 0) since norms are positive finite.
__device__ void mask_tile(const float* __restrict__ emb,
                          unsigned char* __restrict__ mask, int task, float* sm) {
    float* As = sm;             // 32*65
    float* Bs = sm + 32 * 65;   // 16*65
    int tid = threadIdx.x;
    int ib = (task & 31) << 5;
    int jb = (task >> 5) << 4;
    #pragma unroll
    for (int r = 0; r < 2; ++r) {
        int q = tid + (r << 8);
        int row = q >> 4, c4 = (q & 15) << 2;
        float4 a = *(const float4*)&emb[(ib + row) * 64 + c4];
        As[row * 65 + c4 + 0] = a.x; As[row * 65 + c4 + 1] = a.y;
        As[row * 65 + c4 + 2] = a.z; As[row * 65 + c4 + 3] = a.w;
    }
    {
        int row = tid >> 4, c4 = (tid & 15) << 2;
        float4 b = *(const float4*)&emb[(jb + row) * 64 + c4];
        Bs[row * 65 + c4 + 0] = b.x; Bs[row * 65 + c4 + 1] = b.y;
        Bs[row * 65 + c4 + 2] = b.z; Bs[row * 65 + c4 + 3] = b.w;
    }
    __syncthreads();
    int i1 = tid >> 4, j = tid & 15;
    float acc1 = 0.f, acc2 = 0.f;
    #pragma unroll 8
    for (int k = 0; k < 64; ++k) {
        float bv = Bs[j * 65 + k];
        acc1 = fmaf(As[i1 * 65 + k], bv, acc1);
        acc2 = fmaf(As[(i1 + 16) * 65 + k], bv, acc2);
    }
    int gi1 = ib + i1, gi2 = ib + i1 + 16, gj = jb + j;
    mask[gi1 * NN + gj] = (acc1 != 0.f || gi1 == gj) ? 1 : 0;
    mask[gi2 * NN + gj] = (acc2 != 0.f || gi2 == gj) ? 1 : 0;
}

// --- Attention half: TI=2 rows, half of j (js), quad-cooperative ----------
// lane = 4*jl + h; quad shares row j = js*512 + wave*128 + jl*8 + s (8 steps)
// e' = quadsum(sum at'|xr+xv|) + arE + alE[j]; pe = exp2(e') (e bounded).
// Yields (o,l) for tid<128: ii = tid>>6, c = tid&63.
__device__ void attn_half(const float* __restrict__ xl, const float* __restrict__ xr,
                          const float* __restrict__ att, const float* __restrict__ alE,
                          const unsigned char* __restrict__ mask,
                          int p, int js, float* sm, float& oOut, float& lOut) {
    float* sO = sm;          // [ii][16 wk][64]  = 2048 floats
    float* sL = sm + 2048;   // [ii][16 wk][4 q] = 128 floats
    int tid = threadIdx.x;
    int wave = tid >> 6, lane = tid & 63;
    int h = lane & 3, jl = lane >> 2;
    int b  = p >> 9;
    int i0 = (p & 511) << 1;
    int jbase = (js << 9) + (wave << 7) + (jl << 3);

    const float* xlb = xl + (b << 16);
    float at[16], xr0f[16], xr1f[16];
    {
        const float* ap = att + (h << 2);
        const float* r0 = xr + (((b << 10) + i0) << 6) + (h << 2);
        const float* r1 = r0 + 64;
        #pragma unroll
        for (int q = 0; q < 4; ++q) {
            *(float4*)&at[q << 2]   = *(const float4*)(ap + (q << 4));
            *(float4*)&xr0f[q << 2] = *(const float4*)(r0 + (q << 4));
            *(float4*)&xr1f[q << 2] = *(const float4*)(r1 + (q << 4));
        }
        #pragma unroll
        for (int pp = 0; pp < 16; ++pp) at[pp] *= 0.4f * LOG2E;
    }
    float ar0q[4], ar1q[4];
    #pragma unroll
    for (int q = 0; q < 4; ++q) {
        float p0 = 0.f, p1 = 0.f;
        #pragma unroll
        for (int rr = 0; rr < 4; ++rr) {
            p0 = fmaf(at[(q << 2) + rr], xr0f[(q << 2) + rr], p0);
            p1 = fmaf(at[(q << 2) + rr], xr1f[(q << 2) + rr], p1);
        }
        ar0q[q] = 1.5f * quad_sum4(p0);
        ar1q[q] = 1.5f * quad_sum4(p1);
    }
    unsigned mb0 = 0, mb1 = 0;
    {
        const unsigned* m0p = (const unsigned*)(mask + i0 * NN + jbase);
        const unsigned* m1p = (const unsigned*)(mask + (i0 + 1) * NN + jbase);
        #pragma unroll
        for (int q = 0; q < 2; ++q) {
            unsigned w0 = m0p[q], w1 = m1p[q];
            mb0 |= ((((w0 >> 0) & 1) | ((w0 >> 7) & 2) | ((w0 >> 14) & 4) | ((w0 >> 21) & 8)) << (q << 2));
            mb1 |= ((((w1 >> 0) & 1) | ((w1 >> 7) & 2) | ((w1 >> 14) & 4) | ((w1 >> 21) & 8)) << (q << 2));
        }
    }
    float O0[16], O1[16], l0q[4] = {0,0,0,0}, l1q[4] = {0,0,0,0};
    #pragma unroll
    for (int pp = 0; pp < 16; ++pp) { O0[pp] = 0.f; O1[pp] = 0.f; }
    const float* xrow = xlb + (jbase << 6) + (h << 2);
    const float* alp  = alE + (b << 12) + (jbase << 2);
    #pragma unroll 2
    for (int s = 0; s < 8; ++s) {
        const float* rp = xrow + (s << 6);
        float xv[16];
        *(float4*)&xv[0]  = *(const float4*)(rp);
        *(float4*)&xv[4]  = *(const float4*)(rp + 16);
        *(float4*)&xv[8]  = *(const float4*)(rp + 32);
        *(float4*)&xv[12] = *(const float4*)(rp + 48);
        float alr[4];
        *(float4*)alr = *(const float4*)(alp + (s << 2));
        bool m0 = (mb0 >> s) & 1, m1 = (mb1 >> s) & 1;
        #pragma unroll
        for (int q = 0; q < 4; ++q) {
            float p0 = 0.f, p1 = 0.f;
            #pragma unroll
            for (int rr = 0; rr < 4; ++rr) {
                float xvv = xv[(q << 2) + rr];
                float a = at[(q << 2) + rr];
                p0 = fmaf(a, __builtin_fabsf(xr0f[(q << 2) + rr] + xvv), p0);
                p1 = fmaf(a, __builtin_fabsf(xr1f[(q << 2) + rr] + xvv), p1);
            }
            float e0 = quad_sum4(p0) + (ar0q[q] + alr[q]);
            float e1 = quad_sum4(p1) + (ar1q[q] + alr[q]);
            float pe0 = m0 ? __builtin_amdgcn_exp2f(e0) : 0.f;
            float pe1 = m1 ? __builtin_amdgcn_exp2f(e1) : 0.f;
            l0q[q] += pe0; l1q[q] += pe1;
            #pragma unroll
            for (int rr = 0; rr < 4; ++rr) {
                float xvv = xv[(q << 2) + rr];
                O0[(q << 2) + rr] = fmaf(pe0, xvv, O0[(q << 2) + rr]);
                O1[(q << 2) + rr] = fmaf(pe1, xvv, O1[(q << 2) + rr]);
            }
        }
    }
    #pragma unroll
    for (int pp = 0; pp < 16; ++pp) {
        O0[pp] += dpp_mov<0x114>(O0[pp]); O0[pp] += dpp_mov<0x118>(O0[pp]);
        O1[pp] += dpp_mov<0x114>(O1[pp]); O1[pp] += dpp_mov<0x118>(O1[pp]);
    }
    #pragma unroll
    for (int q = 0; q < 4; ++q) {
        l0q[q] += dpp_mov<0x114>(l0q[q]); l0q[q] += dpp_mov<0x118>(l0q[q]);
        l1q[q] += dpp_mov<0x114>(l1q[q]); l1q[q] += dpp_mov<0x118>(l1q[q]);
    }
    if ((lane & 15) >= 12) {
        int k = lane >> 4;
        int wk = (wave << 2) + k;
        #pragma unroll
        for (int q = 0; q < 4; ++q) {
            *(float4*)&sO[(wk)      * 64 + (q << 4) + (h << 2)] = *(const float4*)&O0[q << 2];
            *(float4*)&sO[(16 + wk) * 64 + (q << 4) + (h << 2)] = *(const float4*)&O1[q << 2];
        }
        if (h == 0) {
            #pragma unroll
            for (int q = 0; q < 4; ++q) {
                sL[(wk << 2) + q]      = l0q[q];
                sL[64 + (wk << 2) + q] = l1q[q];
            }
        }
    }
    __syncthreads();
    if (tid < 128) {
        int ii = tid >> 6, c = tid & 63;
        float o = 0.f, l = 0.f;
        #pragma unroll
        for (int wk = 0; wk < 16; ++wk) {
            o += sO[(ii * 16 + wk) * 64 + c];
            l += sL[ii * 64 + (wk << 2) + (c >> 4)];
        }
        oOut = o; lOut = l;
    }
}

// --- K1: mask tile + layer-1 dual-GEMM row + ws zero-init, 2048 blocks ----
__global__ __launch_bounds__(256) void k_p1(const float* __restrict__ x,
                                            const float* __restrict__ emb,
                                            const float* __restrict__ Wl1,
                                            const float* __restrict__ Wr1,
                                            const float* __restrict__ att1,
                                            unsigned char* __restrict__ mask,
                                            float* __restrict__ xl,
                                            float* __restrict__ xr,
                                            float* __restrict__ alE,
                                            float* __restrict__ Opar,
                                            float* __restrict__ lpar,
                                            float* __restrict__ Opar2,
                                            float* __restrict__ lpar2,
                                            int* __restrict__ tick) {
    __shared__ float sm[32 * 65 + 16 * 65];
    __shared__ float hrow[64];
    int bid = blockIdx.x;
    int tid = threadIdx.x;
    // zero the atomic accumulators / tickets for this call (idle threads)
    if (tid >= 128 && tid < 192) {
        int t = tid - 128;
        Opar[bid * 64 + t]  = 0.f;
        Opar2[bid * 64 + t] = 0.f;
    } else if (tid >= 192 && tid < 196) {
        lpar[bid * 4 + (tid - 192)]  = 0.f;
        lpar2[bid * 4 + (tid - 192)] = 0.f;
    } else if (tid == 196) {
        tick[bid] = 0;
    }
    if (tid < 64) hrow[tid] = x[bid * 64 + tid];
    mask_tile(emb, mask, bid, sm);
    __syncthreads();
    if (tid < 64) {
        int c = tid;
        float accl = 0.f, accr = 0.f;
        #pragma unroll 8
        for (int p = 0; p < 64; ++p) {
            float a = hrow[p];
            accl = fmaf(a, Wl1[p * 64 + c], accl);
            accr = fmaf(a, Wr1[p * 64 + c], accr);
        }
        xl[bid * 64 + c] = accl;
        xr[bid * 64 + c] = accr;
        float t = dpp_rowsum16(accl * att1[c]);
        if ((c & 15) == 15) alE[(bid << 2) | (c >> 4)] = 0.6f * LOG2E * t;
    }
}

// --- K2/K3: js-split attention; 2nd arriver per ipair runs the epilogue ---
// L1: epilogue = relu(o/l+b) -> fused layer-2 dual GEMM.  !L1: -> out.
template <bool L1>
__global__ __launch_bounds__(256, 4) void k_attn2(
    const float* __restrict__ xl, const float* __restrict__ xr,
    const float* __restrict__ att, const float* __restrict__ alE,
    const unsigned char* __restrict__ mask, const float* __restrict__ bias,
    const float* __restrict__ Wl2, const float* __restrict__ Wr2,
    const float* __restrict__ att2,
    float* __restrict__ xlo, float* __restrict__ xro, float* __restrict__ alEo,
    float* __restrict__ out,
    float* __restrict__ Opar, float* __restrict__ lpar, int* __restrict__ tick)
{
    __shared__ float sm[2176];
    __shared__ float hrow[2][64];
    __shared__ int sOld;
    int tid = threadIdx.x;
    int js = blockIdx.x & 1;
    int p  = blockIdx.x >> 1;
    float o = 0.f, l = 0.f;
    attn_half(xl, xr, att, alE, mask, p, js, sm, o, l);

    // accumulate partials at the device-coherent point (2 addends/loc)
    if (tid < 128) {
        int ii = tid >> 6, c = tid & 63;
        int idx = (p << 1) | ii;
        atomicAdd(&Opar[idx * 64 + c], o);
        if ((c & 15) == 0) atomicAdd(&lpar[(idx << 2) + (c >> 4)], l);
    }
    __threadfence();
    __syncthreads();
    if (tid == 0) sOld = atomicAdd(&tick[p], 1);
    __syncthreads();
    if (sOld == 0) return;          // first arriver: done (uniform exit)
    __threadfence();

    if (tid < 128) {
        int ii = tid >> 6, c = tid & 63;
        int idx = (p << 1) | ii;
        float oT = atomicAdd(&Opar[idx * 64 + c], 0.0f);          // coherent read
        float lT = atomicAdd(&lpar[(idx << 2) + (c >> 4)], 0.0f); // coherent read
        float res = oT / lT + bias[c];
        if (L1) {
            hrow[ii][c] = fmaxf(res, 0.f);
        } else {
            int g = ((p >> 9) << 10) + ((p & 511) << 1) + ii;
            out[g * 64 + c] = res;
        }
    }
    if (L1) {
        __syncthreads();
        if (tid < 128) {
            int ii = tid >> 6, c = tid & 63;
            int g = ((p >> 9) << 10) + ((p & 511) << 1) + ii;
            const float* hr = hrow[ii];
            float accl = 0.f, accr = 0.f;
            #pragma unroll 8
            for (int pp = 0; pp < 64; ++pp) {
                float a = hr[pp];
                accl = fmaf(a, Wl2[pp * 64 + c], accl);
                accr = fmaf(a, Wr2[pp * 64 + c], accr);
            }
            xlo[g * 64 + c] = accl;
            xro[g * 64 + c] = accr;
            float t = dpp_rowsum16(accl * att2[c]);
            if ((c & 15) == 15) alEo[(g << 2) | (c >> 4)] = 0.6f * LOG2E * t;
        }
    }
}

extern "C" void kernel_launch(void* const* d_in, const int* in_sizes, int n_in,
                              void* d_out, int out_size, void* d_ws, size_t ws_size,
                              hipStream_t stream) {
    const float* x    = (const float*)d_in[0];
    const float* emb  = (const float*)d_in[1];
    const float* Wl1  = (const float*)d_in[2];
    const float* Wr1  = (const float*)d_in[3];
    const float* att1 = (const float*)d_in[4];
    const float* b1   = (const float*)d_in[5];
    const float* Wl2  = (const float*)d_in[6];
    const float* Wr2  = (const float*)d_in[7];
    const float* att2 = (const float*)d_in[8];
    const float* b2   = (const float*)d_in[9];
    float* out = (float*)d_out;

    unsigned char* mask = (unsigned char*)d_ws;        // 1 MB
    float* xl1   = (float*)(mask + NN * NN);           // 512 KB
    float* xr1   = xl1 + 2 * NN * 64;                  // 512 KB
    float* alE1  = xr1 + 2 * NN * 64;                  // 32 KB
    float* xl2   = alE1 + 2 * NN * 4;                  // 512 KB
    float* xr2   = xl2 + 2 * NN * 64;                  // 512 KB
    float* alE2  = xr2 + 2 * NN * 64;                  // 32 KB
    float* Opar  = alE2 + 2 * NN * 4;                  // 512 KB [ipair|ii][64]
    float* lpar  = Opar + 2048 * 64;                   // 32 KB  [ipair|ii][4]
    float* Opar2 = lpar + 2048 * 4;                    // 512 KB
    float* lpar2 = Opar2 + 2048 * 64;                  // 32 KB
    int*   tick  = (int*)(lpar2 + 2048 * 4);           // 8 KB (layer1: [0,1024), layer2: +1024)

    k_p1<<<2048, 256, 0, stream>>>(x, emb, Wl1, Wr1, att1, mask, xl1, xr1, alE1,
                                   Opar, lpar, Opar2, lpar2, tick);
    k_attn2<true><<<2048, 256, 0, stream>>>(xl1, xr1, att1, alE1, mask, b1,
                                            Wl2, Wr2, att2, xl2, xr2, alE2,
                                            nullptr, Opar, lpar, tick);
    k_attn2<false><<<2048, 256, 0, stream>>>(xl2, xr2, att2, alE2, mask, b2,
                                             nullptr, nullptr, nullptr,
                                             nullptr, nullptr, nullptr,
                                             out, Opar2, lpar2, tick + 1024);
}